// Round 1
// baseline (362.628 us; speedup 1.0000x reference)
//
#include <hip/hip_runtime.h>

#define SCALE 0.125f

constexpr int H_ = 16, B_ = 4, L_ = 1024, T_ = 1024, D_ = 64, HB_ = 64;

using f32x4 = __attribute__((ext_vector_type(4))) float;
using half8 = __attribute__((ext_vector_type(8))) _Float16;

__device__ inline half8 ld_half8(const _Float16* p) {
  return *(const half8*)p;
}

// ---------------------------------------------------------------------------
// Kernel 1: per block = 64 query rows (one ltile) x full T for one (h,b).
// Computes Z[row] = sum_t exp(qk*scale + prev) and stores 1/Z in ws.
// ---------------------------------------------------------------------------
__global__ __launch_bounds__(256) void zpass_kernel(
    const float* __restrict__ q, const float* __restrict__ kk,
    const float* __restrict__ prev, float* __restrict__ rz) {
  __shared__ __align__(16) _Float16 Ks[64][72];  // K chunk, f16, padded rows

  const int ltile = blockIdx.x;   // 0..15
  const int hb    = blockIdx.y;   // 0..63
  const int tid   = threadIdx.x;
  const int w   = tid >> 6;       // wave 0..3
  const int l   = tid & 63;       // lane
  const int l15 = l & 15;
  const int lg  = l >> 4;         // 0..3

  // A-fragment rows (q rows) and C/D rows for this lane
  const int qr   = ltile * 64 + w * 16 + l15;
  const int row0 = ltile * 64 + w * 16 + lg * 4;

  // Load Q fragments once: lane holds Q[qr][f*32 + lg*8 + e]
  half8 qa[2];
  {
    const float* qrow = q + ((size_t)hb * L_ + qr) * D_ + lg * 8;
#pragma unroll
    for (int f = 0; f < 2; ++f) {
#pragma unroll
      for (int e = 0; e < 8; ++e) qa[f][e] = (_Float16)qrow[f * 32 + e];
    }
  }

  const float* prow[4];
#pragma unroll
  for (int i = 0; i < 4; ++i)
    prow[i] = prev + ((size_t)hb * L_ + row0 + i) * T_;

  float zacc[4] = {0.f, 0.f, 0.f, 0.f};

  const int sr = tid >> 2;          // staging row 0..63
  const int sc = (tid & 3) * 16;    // staging col 0,16,32,48

  for (int t0 = 0; t0 < T_; t0 += 64) {
    // stage K chunk (64 t-rows x 64 d) as f16
    {
      const float* kp = kk + ((size_t)hb * T_ + t0 + sr) * D_ + sc;
#pragma unroll
      for (int p = 0; p < 4; ++p) {
        float4 v4 = *(const float4*)(kp + p * 4);
        Ks[sr][sc + p * 4 + 0] = (_Float16)v4.x;
        Ks[sr][sc + p * 4 + 1] = (_Float16)v4.y;
        Ks[sr][sc + p * 4 + 2] = (_Float16)v4.z;
        Ks[sr][sc + p * 4 + 3] = (_Float16)v4.w;
      }
    }
    __syncthreads();

#pragma unroll
    for (int nt = 0; nt < 4; ++nt) {
      // B-fragment: lane holds K[t0+nt*16+l15][f*32 + lg*8 + e]
      half8 kb0 = ld_half8(&Ks[nt * 16 + l15][lg * 8]);
      half8 kb1 = ld_half8(&Ks[nt * 16 + l15][32 + lg * 8]);
      f32x4 acc = {0.f, 0.f, 0.f, 0.f};
      acc = __builtin_amdgcn_mfma_f32_16x16x32_f16(qa[0], kb0, acc, 0, 0, 0);
      acc = __builtin_amdgcn_mfma_f32_16x16x32_f16(qa[1], kb1, acc, 0, 0, 0);
      const int t = t0 + nt * 16 + l15;
#pragma unroll
      for (int i = 0; i < 4; ++i)
        zacc[i] += __expf(acc[i] * SCALE + prow[i][t]);
    }
    __syncthreads();
  }

  // reduce Z over the 16 lanes sharing each row (xor within l&15)
#pragma unroll
  for (int m = 1; m < 16; m <<= 1) {
#pragma unroll
    for (int i = 0; i < 4; ++i) zacc[i] += __shfl_xor(zacc[i], m, 64);
  }
  if (l15 == 0) {
#pragma unroll
    for (int i = 0; i < 4; ++i)
      rz[(size_t)hb * L_ + row0 + i] = 1.0f / zacc[i];
  }
}

// ---------------------------------------------------------------------------
// Kernel 2: recompute scores, write normalized attention, and do PV via a
// per-wave LDS round trip for the E (S-layout -> A-fragment) transpose.
// ---------------------------------------------------------------------------
__global__ __launch_bounds__(256) void fused_kernel(
    const float* __restrict__ q, const float* __restrict__ kk,
    const float* __restrict__ vv, const float* __restrict__ prev,
    const float* __restrict__ rz, float* __restrict__ out,
    float* __restrict__ att) {
  __shared__ __align__(16) _Float16 Ks[64][72];      // K chunk rows
  __shared__ __align__(16) _Float16 Vt[64][72];      // V chunk transposed [d][t]
  __shared__ __align__(16) _Float16 El[4][16][72];   // per-wave E tile [q][t]

  const int ltile = blockIdx.x;
  const int hb    = blockIdx.y;
  const int tid   = threadIdx.x;
  const int w   = tid >> 6;
  const int l   = tid & 63;
  const int l15 = l & 15;
  const int lg  = l >> 4;

  const int qr   = ltile * 64 + w * 16 + l15;
  const int row0 = ltile * 64 + w * 16 + lg * 4;

  half8 qa[2];
  {
    const float* qrow = q + ((size_t)hb * L_ + qr) * D_ + lg * 8;
#pragma unroll
    for (int f = 0; f < 2; ++f) {
#pragma unroll
      for (int e = 0; e < 8; ++e) qa[f][e] = (_Float16)qrow[f * 32 + e];
    }
  }

  float rzv[4];
  const float* prow[4];
  float* arow[4];
#pragma unroll
  for (int i = 0; i < 4; ++i) {
    rzv[i]  = rz[(size_t)hb * L_ + row0 + i];
    prow[i] = prev + ((size_t)hb * L_ + row0 + i) * T_;
    arow[i] = att + ((size_t)hb * L_ + row0 + i) * T_;
  }

  f32x4 oacc[4];
#pragma unroll
  for (int nd = 0; nd < 4; ++nd) oacc[nd] = (f32x4){0.f, 0.f, 0.f, 0.f};

  const int sr = tid >> 2;
  const int sc = (tid & 3) * 16;

  for (int t0 = 0; t0 < T_; t0 += 64) {
    // stage K chunk rows (f16)
    {
      const float* kp = kk + ((size_t)hb * T_ + t0 + sr) * D_ + sc;
#pragma unroll
      for (int p = 0; p < 4; ++p) {
        float4 v4 = *(const float4*)(kp + p * 4);
        Ks[sr][sc + p * 4 + 0] = (_Float16)v4.x;
        Ks[sr][sc + p * 4 + 1] = (_Float16)v4.y;
        Ks[sr][sc + p * 4 + 2] = (_Float16)v4.z;
        Ks[sr][sc + p * 4 + 3] = (_Float16)v4.w;
      }
    }
    // stage V chunk transposed: Vt[d][t_local]
    {
      const float* vp = vv + ((size_t)hb * T_ + t0 + sr) * D_ + sc;
#pragma unroll
      for (int p = 0; p < 4; ++p) {
        float4 v4 = *(const float4*)(vp + p * 4);
        Vt[sc + p * 4 + 0][sr] = (_Float16)v4.x;
        Vt[sc + p * 4 + 1][sr] = (_Float16)v4.y;
        Vt[sc + p * 4 + 2][sr] = (_Float16)v4.z;
        Vt[sc + p * 4 + 3][sr] = (_Float16)v4.w;
      }
    }
    __syncthreads();

    // QK^T + softmax numerator; write normalized attention; E -> LDS
#pragma unroll
    for (int nt = 0; nt < 4; ++nt) {
      half8 kb0 = ld_half8(&Ks[nt * 16 + l15][lg * 8]);
      half8 kb1 = ld_half8(&Ks[nt * 16 + l15][32 + lg * 8]);
      f32x4 acc = {0.f, 0.f, 0.f, 0.f};
      acc = __builtin_amdgcn_mfma_f32_16x16x32_f16(qa[0], kb0, acc, 0, 0, 0);
      acc = __builtin_amdgcn_mfma_f32_16x16x32_f16(qa[1], kb1, acc, 0, 0, 0);
      const int t = t0 + nt * 16 + l15;
#pragma unroll
      for (int i = 0; i < 4; ++i) {
        float e = __expf(acc[i] * SCALE + prow[i][t]);
        arow[i][t] = e * rzv[i];                       // normalized attention
        El[w][lg * 4 + i][nt * 16 + l15] = (_Float16)e; // unnormalized E
      }
    }
    __syncthreads();  // El visible (cross-lane), Ks/Vt reads still pending

    // PV: O += E * V  (A-frag from El, B-frag from Vt)
#pragma unroll
    for (int ks = 0; ks < 2; ++ks) {
      half8 ea = ld_half8(&El[w][l15][ks * 32 + lg * 8]);
#pragma unroll
      for (int nd = 0; nd < 4; ++nd) {
        half8 vb = ld_half8(&Vt[nd * 16 + l15][ks * 32 + lg * 8]);
        oacc[nd] = __builtin_amdgcn_mfma_f32_16x16x32_f16(ea, vb, oacc[nd], 0, 0, 0);
      }
    }
    __syncthreads();  // before restaging next chunk
  }

  // epilogue: O = oacc * (1/Z)
#pragma unroll
  for (int nd = 0; nd < 4; ++nd) {
#pragma unroll
    for (int i = 0; i < 4; ++i) {
      out[((size_t)hb * L_ + row0 + i) * D_ + nd * 16 + l15] =
          oacc[nd][i] * rzv[i];
    }
  }
}

extern "C" void kernel_launch(void* const* d_in, const int* in_sizes, int n_in,
                              void* d_out, int out_size, void* d_ws,
                              size_t ws_size, hipStream_t stream) {
  const float* q    = (const float*)d_in[0];  // (H,B,L,D)
  const float* k    = (const float*)d_in[1];  // (H,B,T,D)
  const float* v    = (const float*)d_in[2];  // (H,B,T,D)
  const float* prev = (const float*)d_in[3];  // (H,B,L,T)

  float* out = (float*)d_out;                         // (H,B,L,D)
  float* att = out + (size_t)HB_ * L_ * D_;           // (H,B,L,T)
  float* rz  = (float*)d_ws;                          // HB*L floats

  dim3 grid(L_ / 64, HB_);
  zpass_kernel<<<grid, 256, 0, stream>>>(q, k, prev, rz);
  fused_kernel<<<grid, 256, 0, stream>>>(q, k, v, prev, rz, out, att);
}

// Round 3
// 273.127 us; speedup vs baseline: 1.3277x; 1.3277x over previous
//
#include <hip/hip_runtime.h>

#define SCALE 0.125f

constexpr int L_ = 1024, T_ = 1024, D_ = 64, HB_ = 64;

using f32x4  = __attribute__((ext_vector_type(4))) float;
using half8  = __attribute__((ext_vector_type(8))) _Float16;
using half2v = __attribute__((ext_vector_type(2))) _Float16;

// One block = 64 q-rows (ltile) x full T for one (h,b).
// Phase 1: QK^T + exp, E kept in 128 half2 VGPRs, Z accumulated. No barriers.
// Phase 2: normalize E -> LDS El (per-wave private), PV MFMA with
// double-buffered V staging (load-early/write-late), coalesced att stores.
__global__ __launch_bounds__(256, 2) void attn_kernel(
    const float* __restrict__ q, const float* __restrict__ kk,
    const float* __restrict__ vv, const float* __restrict__ prev,
    float* __restrict__ out, float* __restrict__ att) {
  __shared__ __align__(16) _Float16 Vt[2][64][72];   // V chunk transposed [d][t]
  __shared__ __align__(16) _Float16 El[4][16][72];   // per-wave normalized E

  const int ltile = blockIdx.x;   // 0..15
  const int hb    = blockIdx.y;   // 0..63
  const int tid   = threadIdx.x;
  const int w   = tid >> 6;       // wave 0..3
  const int l   = tid & 63;
  const int l15 = l & 15;
  const int lg  = l >> 4;         // 0..3

  const int qr   = ltile * 64 + w * 16 + l15;   // A-frag row
  const int row0 = ltile * 64 + w * 16 + lg * 4; // C/D rows (4)

  // Q fragments: lane holds Q[qr][f*32 + lg*8 + e]
  half8 qa[2];
  {
    const float* qrow = q + ((size_t)hb * L_ + qr) * D_ + lg * 8;
#pragma unroll
    for (int f = 0; f < 2; ++f)
#pragma unroll
      for (int e = 0; e < 8; ++e) qa[f][e] = (_Float16)qrow[f * 32 + e];
  }

  const float* prow0 = prev + ((size_t)hb * L_ + row0) * (size_t)T_;
  const float* kbase = kk + (size_t)hb * T_ * D_;

  half2v E[128];                       // unnormalized exp(scores), f16-packed
  float zacc[4] = {0.f, 0.f, 0.f, 0.f};

  // ------------------------- Phase 1: scores ------------------------------
#pragma unroll
  for (int c = 0; c < 16; ++c) {
    const int t0 = c * 64;
    // prefetch the 16 prev values this lane needs for the whole chunk
    float pv[4][4];
#pragma unroll
    for (int nt = 0; nt < 4; ++nt)
#pragma unroll
      for (int i = 0; i < 4; ++i)
        pv[nt][i] = prow0[(size_t)i * T_ + t0 + nt * 16 + l15];

#pragma unroll
    for (int nt = 0; nt < 4; ++nt) {
      // K B-fragment direct from global (L2-hot): K[t0+nt*16+l15][d]
      const float* kp = kbase + (size_t)(t0 + nt * 16 + l15) * D_ + lg * 8;
      float4 a0 = *(const float4*)(kp);
      float4 a1 = *(const float4*)(kp + 4);
      float4 b0 = *(const float4*)(kp + 32);
      float4 b1 = *(const float4*)(kp + 36);
      half8 kb0, kb1;
      kb0[0] = (_Float16)a0.x; kb0[1] = (_Float16)a0.y;
      kb0[2] = (_Float16)a0.z; kb0[3] = (_Float16)a0.w;
      kb0[4] = (_Float16)a1.x; kb0[5] = (_Float16)a1.y;
      kb0[6] = (_Float16)a1.z; kb0[7] = (_Float16)a1.w;
      kb1[0] = (_Float16)b0.x; kb1[1] = (_Float16)b0.y;
      kb1[2] = (_Float16)b0.z; kb1[3] = (_Float16)b0.w;
      kb1[4] = (_Float16)b1.x; kb1[5] = (_Float16)b1.y;
      kb1[6] = (_Float16)b1.z; kb1[7] = (_Float16)b1.w;

      f32x4 acc = {0.f, 0.f, 0.f, 0.f};
      acc = __builtin_amdgcn_mfma_f32_16x16x32_f16(qa[0], kb0, acc, 0, 0, 0);
      acc = __builtin_amdgcn_mfma_f32_16x16x32_f16(qa[1], kb1, acc, 0, 0, 0);

      float e0 = __expf(acc[0] * SCALE + pv[nt][0]);
      float e1 = __expf(acc[1] * SCALE + pv[nt][1]);
      float e2 = __expf(acc[2] * SCALE + pv[nt][2]);
      float e3 = __expf(acc[3] * SCALE + pv[nt][3]);
      zacc[0] += e0; zacc[1] += e1; zacc[2] += e2; zacc[3] += e3;
      half2v p0, p1;
      p0[0] = (_Float16)e0; p0[1] = (_Float16)e1;
      p1[0] = (_Float16)e2; p1[1] = (_Float16)e3;
      E[c * 8 + nt * 2 + 0] = p0;
      E[c * 8 + nt * 2 + 1] = p1;
    }
  }

  // Z reduce across the 16 columns (l15) within each lg group
#pragma unroll
  for (int m = 1; m < 16; m <<= 1)
#pragma unroll
    for (int i = 0; i < 4; ++i) zacc[i] += __shfl_xor(zacc[i], m, 64);
  float rzv[4];
#pragma unroll
  for (int i = 0; i < 4; ++i) rzv[i] = 1.0f / zacc[i];

  // ------------------------- Phase 2: att + PV ----------------------------
  const float* vbase = vv + (size_t)hb * T_ * D_;
  const int sr = tid >> 2;          // staging t-row 0..63
  const int sc = (tid & 3) * 16;    // staging d-col 0,16,32,48

  float4 sv[4];
  auto stage_load = [&](int t0) {
    const float* vp = vbase + (size_t)(t0 + sr) * D_ + sc;
    sv[0] = *(const float4*)(vp);
    sv[1] = *(const float4*)(vp + 4);
    sv[2] = *(const float4*)(vp + 8);
    sv[3] = *(const float4*)(vp + 12);
  };
  auto stage_write = [&](int buf) {
#pragma unroll
    for (int p = 0; p < 4; ++p) {
      Vt[buf][sc + p * 4 + 0][sr] = (_Float16)sv[p].x;
      Vt[buf][sc + p * 4 + 1][sr] = (_Float16)sv[p].y;
      Vt[buf][sc + p * 4 + 2][sr] = (_Float16)sv[p].z;
      Vt[buf][sc + p * 4 + 3][sr] = (_Float16)sv[p].w;
    }
  };

  stage_load(0);
  stage_write(0);

  f32x4 oacc[4];
#pragma unroll
  for (int nd = 0; nd < 4; ++nd) oacc[nd] = (f32x4){0.f, 0.f, 0.f, 0.f};

  // this lane's att store base: row (w*16+l15), col block lg*16
  float* attw = att + ((size_t)hb * L_ + ltile * 64 + w * 16 + l15) * T_ + lg * 16;

#pragma unroll
  for (int c = 0; c < 16; ++c) {
    __syncthreads();                 // staged Vt[buf] ready for all waves
    const int buf = c & 1;
    if (c < 15) stage_load((c + 1) * 64);   // issue early (T14)

    // normalized E -> El (per-wave private; same-wave lgkm ordering suffices)
#pragma unroll
    for (int nt = 0; nt < 4; ++nt) {
      half2v p0 = E[c * 8 + nt * 2 + 0];
      half2v p1 = E[c * 8 + nt * 2 + 1];
      El[w][lg * 4 + 0][nt * 16 + l15] = (_Float16)((float)p0[0] * rzv[0]);
      El[w][lg * 4 + 1][nt * 16 + l15] = (_Float16)((float)p0[1] * rzv[1]);
      El[w][lg * 4 + 2][nt * 16 + l15] = (_Float16)((float)p1[0] * rzv[2]);
      El[w][lg * 4 + 3][nt * 16 + l15] = (_Float16)((float)p1[1] * rzv[3]);
    }

    // PV: O += A * V
#pragma unroll
    for (int ks = 0; ks < 2; ++ks) {
      half8 ea = *(const half8*)&El[w][l15][ks * 32 + lg * 8];
#pragma unroll
      for (int nd = 0; nd < 4; ++nd) {
        half8 vb = *(const half8*)&Vt[buf][nd * 16 + l15][ks * 32 + lg * 8];
        oacc[nd] = __builtin_amdgcn_mfma_f32_16x16x32_f16(ea, vb, oacc[nd], 0, 0, 0);
      }
    }

    // att store: lane writes 64B contiguous (row w*16+l15, cols t0+lg*16..+15)
    {
      half8 h0 = *(const half8*)&El[w][l15][lg * 16];
      half8 h1 = *(const half8*)&El[w][l15][lg * 16 + 8];
      float* ap = attw + c * 64;
      float4 s0 = {(float)h0[0], (float)h0[1], (float)h0[2], (float)h0[3]};
      float4 s1 = {(float)h0[4], (float)h0[5], (float)h0[6], (float)h0[7]};
      float4 s2 = {(float)h1[0], (float)h1[1], (float)h1[2], (float)h1[3]};
      float4 s3 = {(float)h1[4], (float)h1[5], (float)h1[6], (float)h1[7]};
      *(float4*)(ap)      = s0;
      *(float4*)(ap + 4)  = s1;
      *(float4*)(ap + 8)  = s2;
      *(float4*)(ap + 12) = s3;
    }

    if (c < 15) stage_write(buf ^ 1);       // write late, before next barrier
  }

  // epilogue: O already normalized (A was normalized)
  float* outw = out + ((size_t)hb * L_ + row0) * D_;
#pragma unroll
  for (int nd = 0; nd < 4; ++nd)
#pragma unroll
    for (int i = 0; i < 4; ++i)
      outw[(size_t)i * D_ + nd * 16 + l15] = oacc[nd][i];
}

extern "C" void kernel_launch(void* const* d_in, const int* in_sizes, int n_in,
                              void* d_out, int out_size, void* d_ws,
                              size_t ws_size, hipStream_t stream) {
  const float* q    = (const float*)d_in[0];  // (H,B,L,D)
  const float* k    = (const float*)d_in[1];  // (H,B,T,D)
  const float* v    = (const float*)d_in[2];  // (H,B,T,D)
  const float* prev = (const float*)d_in[3];  // (H,B,L,T)

  float* out = (float*)d_out;                 // (H,B,L,D)
  float* att = out + (size_t)HB_ * L_ * D_;   // (H,B,L,T)

  dim3 grid(L_ / 64, HB_);
  attn_kernel<<<grid, 256, 0, stream>>>(q, k, v, prev, out, att);
}